// Round 7
// baseline (716.023 us; speedup 1.0000x reference)
//
#include <hip/hip_runtime.h>

// Batched Kalman filter, TWO LANES per element (x-axis lane / y-axis lane).
// The 4x4 system is two identical 2x2 axis blocks coupled only through the
// 2x2 measurement-noise R and the cross-covariance block. Each lane owns:
//   mv,mp  : its axis' (velocity, position) mean
//   s0,s1,s2 : its axis' symmetric 2x2 covariance block
//   w0..w3 : the 2x2 cross-covariance (REAL on x-lane; garbage on y-lane,
//            audited to never flow into any live result)
// 5 shfl_xor(.,1) exchanges per step. 4096 elems * 2 = 8192 threads =
// 128 waves -> 128 CUs active (vs 64 before), ~60 insts/step/lane (vs ~105).
// Staging: global_load_lds j-planes (20 insts / 8-step tile), counted
// vmcnt(8) excludes the 8 newest y-stores (R4/R6-proven pattern).

#define TS 8

__global__ __launch_bounds__(64, 1)
void kalman_pair(const float* __restrict__ zl,
                 const float* __restrict__ mu0,
                 float* __restrict__ out,
                 int N, int T)
{
    // j-plane LDS: [buf][j][step][elem32]; pair lanes read the same word (broadcast)
    __shared__ float lds[2][5][TS][32];

    const int l   = threadIdx.x;
    const int p   = l >> 1;         // element within block, 0..31
    const int isy = l & 1;          // 0 = x-lane, 1 = y-lane
    const int B   = blockIdx.x;
    const int n   = B * 32 + p;

    const float a = 0.999f;         // 1 - (B/M)*DT
    const float c = -0.01f;         // -(K/M)*DT
    const float d = 0.01f;          // DT

    // ---- state ----
    float mv = mu0[n * 4 + isy];        // own velocity mean
    float mp = mu0[n * 4 + 2 + isy];    // own position mean
    float s0 = 1.f, s1 = 0.f, s2 = 1.f; // own sym 2x2 block (vel-vel, vel-pos, pos-pos)
    float w0 = 0.f, w1 = 0.f, w2 = 0.f, w3 = 0.f; // cross block (x-lane real)

    // ---- staging: 20 global_load_lds per tile; inst (j,q) covers 2 steps x 32 elems ----
    auto stage = [&](int buf, int tb) {
        const int s  = 2 * 0 + 0; (void)s;
        #pragma unroll
        for (int j = 0; j < 5; ++j) {
            #pragma unroll
            for (int q = 0; q < 4; ++q) {
                const int ss = 2 * q + (l >> 5);
                const int e  = l & 31;
                const float* g = zl + ((size_t)(tb + ss) * N + B * 32 + e) * 5 + j;
                __builtin_amdgcn_global_load_lds(
                    (const __attribute__((address_space(1))) unsigned int*)g,
                    (__attribute__((address_space(3))) unsigned int*)&lds[buf][j][2 * q][0],
                    4, 0, 0);
            }
        }
    };

    // per-lane ds_read word offsets (each lane reads only its 3 inputs)
    const float* Lb0 = &lds[0][0][0][0];
    const float* Lb1 = &lds[1][0][0][0];
    const int zoff = (isy ? 1 : 0) * (TS * 32) + p;   // z_own plane
    const int ooff = (isy ? 4 : 2) * (TS * 32) + p;   // own Cholesky diag log (L0 or L2)
    const int moff = 3 * (TS * 32) + p;               // L1 (shared off-diag)

    // prologue: tile 0 resident
    stage(0, 0);
    asm volatile("s_waitcnt vmcnt(0)" ::: "memory");

    const int NT = T / TS;
    for (int tile = 0; tile < NT; ++tile) {
        const int b = tile & 1;
        const float* Lb = b ? Lb1 : Lb0;

        // drain this tile's 20 loads; keep the 8 newest VMEM (y stores) in flight
        asm volatile("s_waitcnt vmcnt(8)" ::: "memory");

        // batched LDS -> reg (24 ds_read_b32, compile-time indexed)
        float rz[TS], ro[TS], rm[TS];
        #pragma unroll
        for (int s = 0; s < TS; ++s) {
            rz[s] = Lb[zoff + s * 32];
            ro[s] = Lb[ooff + s * 32];
            rm[s] = Lb[moff + s * 32];
        }

        // prefetch next tile (reload tile 0 at the end to keep counts uniform)
        {
            const int nt = (tile + 1 < NT) ? (tile + 1) : 0;
            stage(b ^ 1, nt * TS);
        }

        float* yp = out + (size_t)(tile * TS) * 2 * N + (size_t)B * 64 + l;

        #pragma unroll
        for (int s = 0; s < TS; ++s) {
            const float z_own = rz[s], Lown = ro[s], L1v = rm[s];

            // ---- predict mean (own axis) ----
            float mpv = a * mv + c * mp;
            float mpp = d * mv + mp;

            // ---- predict own sym block: P' = A2 P A2^T + diag(1,0) ----
            float M0 = a * s0 + c * s1, M1 = a * s1 + c * s2;
            float M2 = d * s0 + s1,     M3 = d * s1 + s2;
            float s0p = a * M0 + (c * M1 + 1.0f);
            float s1p = d * M0 + M1;
            float s2p = d * M2 + M3;

            // ---- predict cross block (x-lane real): W' = A2 W A2^T ----
            float t0 = a * w0 + c * w2, t1 = a * w1 + c * w3;
            float t2 = d * w0 + w2,     t3 = d * w1 + w3;
            float w0p = a * t0 + c * t1;
            float w1p = d * t0 + t1;
            float w2p = a * t2 + c * t3;
            float w3p = d * t2 + t3;

            // ---- exchange: x sends (w2p,w3p); y sends (s1p,s2p)=(v1p,v2p) ----
            float sendA = isy ? s1p : w2p;
            float recvA = __shfl_xor(sendA, 1);
            float sendB = isy ? s2p : w3p;
            float recvB = __shfl_xor(sendB, 1);

            // ---- R from Cholesky: x: R00=l00^2 ; y: R11=l10^2+l11^2 ----
            float le = __expf(Lown);
            float tt = isy ? L1v : 0.0f;
            float Rd = le * le + tt * tt;

            // ---- S diag (own) + off-diag (x computes, y receives) ----
            float S_own = s2p + Rd;
            float S_oth = __shfl_xor(S_own, 1);
            float S01x  = le * L1v + w3p;          // real on x-lane
            float S01r  = __shfl_xor(S01x, 1);
            float S01   = isy ? S01r : S01x;

            float det = S_own * S_oth - S01 * S01;
            float inv = __builtin_amdgcn_rcpf(det);
            float iSa =  S_oth * inv;   // own-first diag of Sinv
            float iSb = -S01 * inv;
            float iSc =  S_own * inv;

            // ---- K rows (own-obs-first ordering; identical code both lanes) ----
            float bv = isy ? recvA : w1p;   // vel-row cross term
            float bp = isy ? recvB : w3p;   // pos-row cross term
            float Kv0 = s1p * iSa + bv * iSb;
            float Kv1 = s1p * iSb + bv * iSc;
            float Kp0 = s2p * iSa + bp * iSb;
            float Kp1 = s2p * iSb + bp * iSc;

            // ---- innovation + mean update ----
            float in_own = z_own - mpp;
            float in_oth = __shfl_xor(in_own, 1);
            mv = mpv + Kv0 * in_own + Kv1 * in_oth;
            mp = mpp + Kp0 * in_own + Kp1 * in_oth;

            // ---- own sym block update ----
            s0 = s0p - Kv0 * s1p - Kv1 * bv;
            s1 = s1p - Kv0 * s2p - Kv1 * bp;
            s2 = s2p - Kp0 * s2p - Kp1 * bp;

            // ---- cross block update (x-lane real; y-lane garbage, never read) ----
            w0 = w0p - Kv0 * w2p - Kv1 * recvA;
            w1 = w1p - Kv0 * w3p - Kv1 * recvB;
            w2 = w2p - Kp0 * w2p - Kp1 * recvA;
            w3 = w3p - Kp0 * w3p - Kp1 * recvB;

            // ---- emit own position mean: out[(t*N+n)*2+isy] = t*2N + B*64 + l ----
            *yp = mp;
            yp += (size_t)2 * N;
        }
    }
}

extern "C" void kernel_launch(void* const* d_in, const int* in_sizes, int n_in,
                              void* d_out, int out_size, void* d_ws, size_t ws_size,
                              hipStream_t stream) {
    const float* zl  = (const float*)d_in[0];
    const float* mu0 = (const float*)d_in[1];
    float* out = (float*)d_out;

    int N = in_sizes[1] / 4;             // 4096
    int T = in_sizes[0] / (N * 5);       // 2048

    int block = 64;                      // 32 elements * 2 lanes
    int grid  = N / 32;                  // 128 blocks -> 128 CUs, 1 wave each
    kalman_pair<<<grid, block, 0, stream>>>(zl, mu0, out, N, T);
}